// Round 8
// baseline (237.031 us; speedup 1.0000x reference)
//
#include <hip/hip_runtime.h>
#include <math.h>

#define B_    8
#define CIN   64
#define COUT  128
#define H_    130
#define NPIX  (H_*H_)            // 16900
#define NPX   (B_*NPIX)          // 135200 flat pixels
#define IMW   132                // padded img height (zero top/bottom rows)
#define SLABU 4608               // ushorts per (yy,xh) slab = 8 cg * 72 col * 8 ci
#define RSTRIP 2                 // output rows per conv block

typedef __attribute__((ext_vector_type(8))) short short8;   // 8 bf16 (A/B frag)
typedef __attribute__((ext_vector_type(4))) float f32x4;    // MFMA acc

__device__ __forceinline__ ushort f2bf(float f) {
    uint u = __builtin_bit_cast(uint, f);
    uint r = (u + 0x7FFFu + ((u >> 16) & 1u)) >> 16;
    return (ushort)r;
}

// ------ BN stage 1 (per-(c,b) plane sum/sumsq) + fused weight prep ------------
__global__ __launch_bounds__(256) void bnw_stage1(
    const float* __restrict__ x, const float* __restrict__ w,
    float* __restrict__ part, ushort* __restrict__ wT)
{
    const int c = blockIdx.x, b = blockIdx.y, tid = threadIdx.x;
    const int flat = b*64 + c;
    if (flat < 288) {                            // wprep: 288*256 = 73728
        int i = flat*256 + tid;
        int co = i / 576, k = i - co*576;
        int dydx = k >> 6, ci = k & 63;
        wT[i] = f2bf(w[co*576 + ci*9 + dydx]);
    }
    const float4* p = (const float4*)(x + ((size_t)b*CIN + c)*NPIX);
    float s = 0.f, q = 0.f;
    for (int i = tid; i < NPIX/4; i += 256) {    // 4225 exactly
        float4 v = p[i];
        s += v.x + v.y + v.z + v.w;
        q += v.x*v.x + v.y*v.y + v.z*v.z + v.w*v.w;
    }
    #pragma unroll
    for (int off = 32; off; off >>= 1) { s += __shfl_down(s, off); q += __shfl_down(q, off); }
    __shared__ float ss[4], qq[4];
    if ((tid & 63) == 0) { ss[tid >> 6] = s; qq[tid >> 6] = q; }
    __syncthreads();
    if (tid == 0) {
        s = ss[0] + ss[1] + ss[2] + ss[3];
        q = qq[0] + qq[1] + qq[2] + qq[3];
        part[(c*B_ + b)*2]     = s;
        part[(c*B_ + b)*2 + 1] = q;
    }
}

// -------- binfold v4: BN-apply + bin_active + col2im, stage2 fused ------------
// img layout: [b][yy(132)][xh(2)][cg(8)][col(72)][ci8] bf16.
//   col c of half xh <-> padded xx = 65*xh + c. Rows yy=0/131, cols xx=0/131
//   are the zero ring; cols 68..71 are pad (never read).
__global__ __launch_bounds__(256) void binfold(
    const float* __restrict__ x, const float* __restrict__ part,
    const float* __restrict__ gamma, const float* __restrict__ beta,
    ushort* __restrict__ img)
{
    __shared__ __align__(16) ushort tile[H_*18];   // [xp][ci16 +2 pad]
    __shared__ float absrow[4][132];
    __shared__ float wsum[4][24];
    __shared__ float sA[4][4], sBt[4][4];
    const int yy = blockIdx.x, b = blockIdx.y, zg = blockIdx.z;
    const int tid = threadIdx.x, wv = tid >> 6, lane = tid & 63;
    const int cgBase = zg*2;
    uint* u0 = (uint*)(img + ((size_t)(b*IMW + yy)*2)*SLABU);

    if (yy == 0 || yy == IMW-1) {                  // border row: zero our slice
        for (int i = tid; i < 1088; i += 256) {
            int xhh = i / 544, r = i - xhh*544, c = r >> 3, p = r & 7;
            u0[(size_t)xhh*(SLABU/2) + ((cgBase + (p>>2))*72 + c)*4 + (p&3)] = 0u;
        }
        return;
    }
    const int y = yy - 1;
    const float county = (float)min(min(y + 1, 3), H_ - y);

    // fused BN stage 2: lanes 0..3 derive affine a,b for this wave's 4 ci
    const int ci0 = zg*16 + wv*4;
    if (lane < 4) {
        int ci = ci0 + lane;
        float s = 0.f, q = 0.f;
        #pragma unroll
        for (int bb = 0; bb < B_; ++bb) {
            s += part[(ci*B_ + bb)*2];
            q += part[(ci*B_ + bb)*2 + 1];
        }
        float mean = s * (1.0f/135200.f);
        float var  = q * (1.0f/135200.f) - mean*mean;
        float a = gamma[ci] / sqrtf(var + 1e-4f);
        sA[wv][lane]  = a;
        sBt[wv][lane] = beta[ci] - mean * a;
    }
    asm volatile("s_waitcnt lgkmcnt(0)" ::: "memory");

    // hoisted loads: 4 ci rows per wave, all issued up-front
    float v0[4], v1[4], v2[4];
    #pragma unroll
    for (int it = 0; it < 4; ++it) {
        const int ci = ci0 + it;
        const float* row = x + (((size_t)b*CIN + ci)*H_ + y)*H_;
        const float a = sA[wv][it], bb = sBt[wv][it];
        v0[it] = a*row[lane]      + bb;
        v1[it] = a*row[lane + 64] + bb;
        v2[it] = (lane < 2) ? (a*row[lane + 128] + bb) : 0.f;
    }

    #pragma unroll
    for (int it = 0; it < 4; ++it) {
        const int cl = wv*4 + it;                  // ci_l within block, 0..15
        absrow[wv][lane]      = fabsf(v0[it]);
        absrow[wv][lane + 64] = fabsf(v1[it]);
        if (lane < 2) absrow[wv][lane + 128] = fabsf(v2[it]);
        asm volatile("s_waitcnt lgkmcnt(0)" ::: "memory");
        if (lane < 24) {
            int j = lane >> 3, bx = lane & 7;
            int s = j + bx*16;
            float acc = 0.f;
            #pragma unroll
            for (int t = 0; t < 16; ++t) acc += absrow[wv][s + t];
            wsum[wv][j*8 + bx] = acc;
        }
        asm volatile("s_waitcnt lgkmcnt(0)" ::: "memory");
        #pragma unroll
        for (int rep = 0; rep < 3; ++rep) {
            int xp = lane + rep*64;
            if (xp < H_) {
                float v = (rep == 0) ? v0[it] : (rep == 1) ? v1[it] : v2[it];
                float sgn = (v > 0.f) ? 1.f : ((v < 0.f) ? -1.f : 0.f);
                float sum = 0.f;
                #pragma unroll
                for (int j = 0; j < 3; ++j) {
                    int ox = xp - j;
                    if ((unsigned)ox < 128u) sum += wsum[wv][j*8 + (ox >> 4)];
                }
                tile[xp*18 + cl] = f2bf(sgn * county * sum * 0.0625f);
            }
        }
        asm volatile("s_waitcnt lgkmcnt(0)" ::: "memory");   // absrow reuse guard
    }
    __syncthreads();
    // store our cg pair into both half-slabs (halo columns duplicated)
    const uint* tU = (const uint*)tile;
    for (int i = tid; i < 1088; i += 256) {
        int xhh = i / 544, r = i - xhh*544, c = r >> 3, p = r & 7;
        int xx = xhh*65 + c;
        if (xx > 131) continue;                    // xh=1, c=67 -> out of range
        uint v = 0u;
        if (xx != 0 && xx != 131) v = tU[(xx-1)*9 + p];
        u0[(size_t)xhh*(SLABU/2) + ((cgBase + (p>>2))*72 + c)*4 + (p&3)] = v;
    }
}

// ---------------- conv v6: A-in-registers, 2-row strips, one-shot DMA ---------
// Block = (xh, ystrip, b). LDS: 4 slabs (padded rows y0..y0+3, 36.9 KB) staged
// once via 36 x 1KB global_load_lds chunks -> 3-4 blocks/CU. Each wave holds
// all 36 A fragments; zero global loads in the k-loop. 4 waves = co-quarters;
// wave tile = 32 co x 65 px per row; 65 strips x 2 rows = 130 exactly.
__global__ __launch_bounds__(256, 3) void conv_mfma(
    const ushort* __restrict__ img, const ushort* __restrict__ wT,
    const float* __restrict__ bias, float* __restrict__ out)
{
    __shared__ __align__(64) ushort sB[4*SLABU];   // 36864 B
    const int xh = blockIdx.x, ys = blockIdx.y, b = blockIdx.z;
    const int y0 = ys*RSTRIP;
    const int tid = threadIdx.x, lane = tid & 63, q = tid >> 6;
    const int l16 = lane & 15, quad = lane >> 4;

    // ---- one-shot async DMA: 36 chunks of 1 KB (SLABU = 9*512)
    #pragma unroll
    for (int t = 0; t < 9; ++t) {
        int k = q + 4*t;                           // 0..35 exactly
        int sl = (int)((unsigned)k / 9u), j = k - sl*9;
        const ushort* gs = img + ((size_t)(b*IMW + y0 + sl)*2 + xh)*SLABU
                           + j*512 + lane*8;
        __builtin_amdgcn_global_load_lds(
            (const __attribute__((address_space(1))) uint*)gs,
            (__attribute__((address_space(3))) uint*)(sB + k*512), 16, 0, 0);
    }

    // ---- A fragments: load all 36 once (complete at the barrier's vmcnt(0))
    const ushort* wA = wT + (size_t)(q*32 + l16)*576 + quad*8;
    short8 aReg[36];
    #pragma unroll
    for (int mt = 0; mt < 2; ++mt)
        #pragma unroll
        for (int s = 0; s < 18; ++s)
            aReg[mt*18 + s] = *(const short8*)(wA + mt*16*576 + s*32);

    float bv[8];
    #pragma unroll
    for (int mt = 0; mt < 2; ++mt)
        #pragma unroll
        for (int rr = 0; rr < 4; ++rr)
            bv[mt*4 + rr] = bias[q*32 + mt*16 + quad*4 + rr];

    int colB[5];
    #pragma unroll
    for (int nt = 0; nt < 5; ++nt)
        colB[nt] = min(nt*16 + l16, 64);           // clamp waste lanes of nt=4

    __syncthreads();

    #pragma unroll
    for (int r = 0; r < RSTRIP; ++r) {
        const int y = y0 + r;                      // always < 130
        f32x4 acc[2][5];
        #pragma unroll
        for (int mt = 0; mt < 2; ++mt)
            #pragma unroll
            for (int nt = 0; nt < 5; ++nt)
                acc[mt][nt] = (f32x4){0.f, 0.f, 0.f, 0.f};

        #pragma unroll
        for (int s = 0; s < 18; ++s) {
            const int dydx = s >> 1, h = s & 1;
            const int dy = dydx / 3, dx = dydx - dy*3;
            const int base = (r + dy)*SLABU + ((h*4 + quad)*72 + dx)*8;
            short8 bf[5];
            #pragma unroll
            for (int nt = 0; nt < 5; ++nt)
                bf[nt] = *(const short8*)(sB + base + colB[nt]*8);
            #pragma unroll
            for (int mt = 0; mt < 2; ++mt)
                #pragma unroll
                for (int nt = 0; nt < 5; ++nt)
                    acc[mt][nt] = __builtin_amdgcn_mfma_f32_16x16x32_bf16(
                        aReg[mt*18 + s], bf[nt], acc[mt][nt], 0, 0, 0);
        }

        const size_t ob = (size_t)b*COUT*NPIX + (size_t)y*H_ + xh*65;
        #pragma unroll
        for (int mt = 0; mt < 2; ++mt) {
            #pragma unroll
            for (int rr = 0; rr < 4; ++rr) {
                const int co = q*32 + mt*16 + quad*4 + rr;
                #pragma unroll
                for (int nt = 0; nt < 5; ++nt) {
                    int p = nt*16 + l16;
                    if (p < 65) {
                        float v = acc[mt][nt][rr] + bv[mt*4 + rr];
                        out[ob + (size_t)co*NPIX + p] = v > 0.f ? v : 0.f;
                    }
                }
            }
        }
    }
}

// ------------------------------------------------------------------------------
extern "C" void kernel_launch(void* const* d_in, const int* in_sizes, int n_in,
                              void* d_out, int out_size, void* d_ws, size_t ws_size,
                              hipStream_t stream)
{
    const float* x      = (const float*)d_in[0];
    const float* gamma  = (const float*)d_in[1];
    const float* beta   = (const float*)d_in[2];
    const float* conv_w = (const float*)d_in[3];
    const float* conv_b = (const float*)d_in[4];
    float* out = (float*)d_out;

    float*  part = (float*)d_ws;            // 1024 f32
    ushort* wT   = (ushort*)(part + 1024);  // 73728 bf16 (byte offset 4096)
    ushort* img  = wT + 73728;              // 8*132*2*4608 bf16 = 19,464,192 B

    bnw_stage1<<<dim3(CIN, B_), 256, 0, stream>>>(x, conv_w, part, wT);
    binfold<<<dim3(IMW, B_, 4), 256, 0, stream>>>(x, part, gamma, beta, img);
    conv_mfma<<<dim3(2, H_/RSTRIP, B_), 256, 0, stream>>>(img, wT, conv_b, out);
}